// Round 1
// baseline (1801.529 us; speedup 1.0000x reference)
//
#include <hip/hip_runtime.h>
#include <hip/hip_bf16.h>
#include <math.h>

#define N_NODES 50000
#define N_EDGES 800000
#define FIN 128
#define FOUT 64
#define NH 8
#define ALPHA 0.2f
#define HSTRIDE (NH * FOUT)  // 512

// ---------------- Kernel 1: per-head projection h[n][head][o] = sum_f x[n][f] * W[head][f][o]
__global__ __launch_bounds__(256) void gat_proj(const float* __restrict__ x,
                                                const float* __restrict__ W,
                                                float* __restrict__ hout) {
    __shared__ float xs[FIN][68];        // x tile transposed: xs[f][n_local], padded row (272B, 16B-aligned)
    __shared__ float ws[FIN * FOUT];     // W[head] as [f][o]

    const int t  = threadIdx.x;
    const int n0 = blockIdx.x * 64;

    // load x tile (64 nodes x 128 feats), transposed into LDS
    {
        const int f0  = (t & 31) * 4;
        const int nl0 = t >> 5;
#pragma unroll
        for (int pass = 0; pass < 8; ++pass) {
            const int nl = nl0 + pass * 8;
            const int n  = n0 + nl;
            float4 v = make_float4(0.f, 0.f, 0.f, 0.f);
            if (n < N_NODES) v = *(const float4*)(x + (size_t)n * FIN + f0);
            xs[f0 + 0][nl] = v.x;
            xs[f0 + 1][nl] = v.y;
            xs[f0 + 2][nl] = v.z;
            xs[f0 + 3][nl] = v.w;
        }
    }

    const int tx = (t & 15) * 4;   // output col base
    const int ty = (t >> 4) * 4;   // node row base

    for (int head = 0; head < NH; ++head) {
        __syncthreads();   // protect ws reuse across heads
        {
            const float4* wg = (const float4*)(W + (size_t)head * FIN * FOUT);
            float4* wl = (float4*)ws;
#pragma unroll
            for (int i = 0; i < 8; ++i) wl[t + i * 256] = wg[t + i * 256];
        }
        __syncthreads();

        float acc[4][4] = {{0.f}};
#pragma unroll 4
        for (int f = 0; f < FIN; ++f) {
            const float4 xv = *(const float4*)&xs[f][ty];
            const float4 wv = *(const float4*)&ws[f * FOUT + tx];
            acc[0][0] += xv.x * wv.x; acc[0][1] += xv.x * wv.y; acc[0][2] += xv.x * wv.z; acc[0][3] += xv.x * wv.w;
            acc[1][0] += xv.y * wv.x; acc[1][1] += xv.y * wv.y; acc[1][2] += xv.y * wv.z; acc[1][3] += xv.y * wv.w;
            acc[2][0] += xv.z * wv.x; acc[2][1] += xv.z * wv.y; acc[2][2] += xv.z * wv.z; acc[2][3] += xv.z * wv.w;
            acc[3][0] += xv.w * wv.x; acc[3][1] += xv.w * wv.y; acc[3][2] += xv.w * wv.z; acc[3][3] += xv.w * wv.w;
        }

#pragma unroll
        for (int i = 0; i < 4; ++i) {
            const int n = n0 + ty + i;
            if (n < N_NODES) {
                float4 o4 = make_float4(acc[i][0], acc[i][1], acc[i][2], acc[i][3]);
                *(float4*)(hout + (size_t)n * HSTRIDE + head * FOUT + tx) = o4;
            }
        }
    }
}

// ---------------- Kernel 2: scores  ssrc[n*8+h] = dot(h[n][h][:], a[h][:64]), sdst with a[h][64:]
__global__ __launch_bounds__(256) void gat_score(const float* __restrict__ h,
                                                 const float* __restrict__ a,
                                                 float* __restrict__ ssrc,
                                                 float* __restrict__ sdst) {
    const int wid  = (int)((blockIdx.x * 256 + threadIdx.x) >> 6);
    const int lane = threadIdx.x & 63;
    if (wid >= N_NODES * NH) return;
    const int n    = wid >> 3;
    const int head = wid & 7;

    const float hv = h[(size_t)n * HSTRIDE + head * FOUT + lane];
    float p1 = hv * a[head * (2 * FOUT) + lane];
    float p2 = hv * a[head * (2 * FOUT) + FOUT + lane];
#pragma unroll
    for (int off = 32; off > 0; off >>= 1) {
        p1 += __shfl_down(p1, off, 64);
        p2 += __shfl_down(p2, off, 64);
    }
    if (lane == 0) {
        ssrc[wid] = p1;
        sdst[wid] = p2;
    }
}

// ---------------- Kernel 3: edge phase. One wave per edge.
__global__ __launch_bounds__(256) void gat_edge(const int* __restrict__ src,
                                                const int* __restrict__ dst,
                                                const float* __restrict__ h,
                                                const float* __restrict__ ssrc,
                                                const float* __restrict__ sdst,
                                                float* __restrict__ acc,      // d_out, pre-zeroed
                                                float* __restrict__ rowsum) { // pre-zeroed
    const int wid  = (int)((blockIdx.x * 256 + threadIdx.x) >> 6);
    const int lane = threadIdx.x & 63;
    if (wid >= N_EDGES) return;

    const int s = src[wid];
    const int d = dst[wid];

    float comb = 0.f;
    if (lane < 16) comb = (lane < 8) ? ssrc[s * 8 + lane] : sdst[d * 8 + (lane - 8)];

    const float* hd = h   + (size_t)d * HSTRIDE;
    float*       po = acc + (size_t)s * HSTRIDE;

#pragma unroll
    for (int hh = 0; hh < NH; ++hh) {
        const float sv = __shfl(comb, hh, 64) + __shfl(comb, 8 + hh, 64);
        const float lr = sv > 0.f ? sv : ALPHA * sv;
        const float e  = __expf(-lr);
        const float hv = hd[hh * FOUT + lane];
        unsafeAtomicAdd(po + hh * FOUT + lane, e * hv);
        if (lane == hh) unsafeAtomicAdd(rowsum + s * 8 + hh, e);
    }
}

// ---------------- Kernel 4: normalize in place. out[i] /= rowsum[i>>6]
__global__ __launch_bounds__(256) void gat_final(float* __restrict__ out,
                                                 const float* __restrict__ rowsum) {
    const size_t i4 = (size_t)blockIdx.x * 256 + threadIdx.x;
    const size_t i  = i4 * 4;
    if (i >= (size_t)N_NODES * HSTRIDE) return;
    float4 v = *(float4*)(out + i);
    const float inv = 1.0f / rowsum[i >> 6];
    v.x *= inv; v.y *= inv; v.z *= inv; v.w *= inv;
    *(float4*)(out + i) = v;
}

extern "C" void kernel_launch(void* const* d_in, const int* in_sizes, int n_in,
                              void* d_out, int out_size, void* d_ws, size_t ws_size,
                              hipStream_t stream) {
    const float* x    = (const float*)d_in[0];
    const int*   edge = (const int*)d_in[1];
    const float* W    = (const float*)d_in[2];
    const float* a    = (const float*)d_in[3];
    float*       out  = (float*)d_out;

    char* ws = (char*)d_ws;
    float* h = (float*)ws;
    size_t off = (size_t)N_NODES * HSTRIDE * sizeof(float);   // 102.4 MB
    float* ssrc = (float*)(ws + off); off += (size_t)N_NODES * NH * sizeof(float);
    float* sdst = (float*)(ws + off); off += (size_t)N_NODES * NH * sizeof(float);
    float* rowsum = (float*)(ws + off);

    const int* srcv = edge;
    const int* dstv = edge + N_EDGES;

    // accumulators must start at zero every call
    hipMemsetAsync(d_out, 0, (size_t)out_size * sizeof(float), stream);
    hipMemsetAsync(rowsum, 0, (size_t)N_NODES * NH * sizeof(float), stream);

    gat_proj<<<(N_NODES + 63) / 64, 256, 0, stream>>>(x, W, h);
    gat_score<<<(N_NODES * NH + 3) / 4, 256, 0, stream>>>(h, a, ssrc, sdst);
    gat_edge<<<(N_EDGES + 3) / 4, 256, 0, stream>>>(srcv, dstv, h, ssrc, sdst, out, rowsum);
    gat_final<<<(N_NODES * HSTRIDE / 4 + 255) / 256, 256, 0, stream>>>(out, rowsum);
}

// Round 2
// 735.134 us; speedup vs baseline: 2.4506x; 2.4506x over previous
//
#include <hip/hip_runtime.h>
#include <hip/hip_bf16.h>
#include <math.h>

#define N_NODES 50000
#define N_EDGES 800000
#define FIN 128
#define FOUT 64
#define NH 8
#define ALPHA 0.2f
#define HSTRIDE (NH * FOUT)  // 512
#define SCAN_T 1024
#define SCAN_CHUNK ((N_NODES + SCAN_T - 1) / SCAN_T)  // 49

// ---------------- Kernel 1: per-head projection h[n][head][o] = sum_f x[n][f] * W[head][f][o]
__global__ __launch_bounds__(256) void gat_proj(const float* __restrict__ x,
                                                const float* __restrict__ W,
                                                float* __restrict__ hout) {
    __shared__ float xs[FIN][68];
    __shared__ float ws[FIN * FOUT];

    const int t  = threadIdx.x;
    const int n0 = blockIdx.x * 64;

    {
        const int f0  = (t & 31) * 4;
        const int nl0 = t >> 5;
#pragma unroll
        for (int pass = 0; pass < 8; ++pass) {
            const int nl = nl0 + pass * 8;
            const int n  = n0 + nl;
            float4 v = make_float4(0.f, 0.f, 0.f, 0.f);
            if (n < N_NODES) v = *(const float4*)(x + (size_t)n * FIN + f0);
            xs[f0 + 0][nl] = v.x;
            xs[f0 + 1][nl] = v.y;
            xs[f0 + 2][nl] = v.z;
            xs[f0 + 3][nl] = v.w;
        }
    }

    const int tx = (t & 15) * 4;
    const int ty = (t >> 4) * 4;

    for (int head = 0; head < NH; ++head) {
        __syncthreads();
        {
            const float4* wg = (const float4*)(W + (size_t)head * FIN * FOUT);
            float4* wl = (float4*)ws;
#pragma unroll
            for (int i = 0; i < 8; ++i) wl[t + i * 256] = wg[t + i * 256];
        }
        __syncthreads();

        float acc[4][4] = {{0.f}};
#pragma unroll 4
        for (int f = 0; f < FIN; ++f) {
            const float4 xv = *(const float4*)&xs[f][ty];
            const float4 wv = *(const float4*)&ws[f * FOUT + tx];
            acc[0][0] += xv.x * wv.x; acc[0][1] += xv.x * wv.y; acc[0][2] += xv.x * wv.z; acc[0][3] += xv.x * wv.w;
            acc[1][0] += xv.y * wv.x; acc[1][1] += xv.y * wv.y; acc[1][2] += xv.y * wv.z; acc[1][3] += xv.y * wv.w;
            acc[2][0] += xv.z * wv.x; acc[2][1] += xv.z * wv.y; acc[2][2] += xv.z * wv.z; acc[2][3] += xv.z * wv.w;
            acc[3][0] += xv.w * wv.x; acc[3][1] += xv.w * wv.y; acc[3][2] += xv.w * wv.z; acc[3][3] += xv.w * wv.w;
        }

#pragma unroll
        for (int i = 0; i < 4; ++i) {
            const int n = n0 + ty + i;
            if (n < N_NODES) {
                float4 o4 = make_float4(acc[i][0], acc[i][1], acc[i][2], acc[i][3]);
                *(float4*)(hout + (size_t)n * HSTRIDE + head * FOUT + tx) = o4;
            }
        }
    }
}

// ---------------- Kernel 2: scores
__global__ __launch_bounds__(256) void gat_score(const float* __restrict__ h,
                                                 const float* __restrict__ a,
                                                 float* __restrict__ ssrc,
                                                 float* __restrict__ sdst) {
    const int wid  = (int)((blockIdx.x * 256 + threadIdx.x) >> 6);
    const int lane = threadIdx.x & 63;
    if (wid >= N_NODES * NH) return;
    const int n    = wid >> 3;
    const int head = wid & 7;

    const float hv = h[(size_t)n * HSTRIDE + head * FOUT + lane];
    float p1 = hv * a[head * (2 * FOUT) + lane];
    float p2 = hv * a[head * (2 * FOUT) + FOUT + lane];
#pragma unroll
    for (int off = 32; off > 0; off >>= 1) {
        p1 += __shfl_down(p1, off, 64);
        p2 += __shfl_down(p2, off, 64);
    }
    if (lane == 0) {
        ssrc[wid] = p1;
        sdst[wid] = p2;
    }
}

// ---------------- CSR build: histogram of src
__global__ __launch_bounds__(256) void gat_hist(const int* __restrict__ src,
                                                int* __restrict__ deg) {
    const int e = blockIdx.x * 256 + threadIdx.x;
    if (e < N_EDGES) atomicAdd(&deg[src[e]], 1);
}

// ---------------- CSR build: exclusive scan (single block)
__global__ __launch_bounds__(SCAN_T) void gat_scan(const int* __restrict__ deg,
                                                   int* __restrict__ row_start,
                                                   int* __restrict__ cursor) {
    __shared__ int part[SCAN_T];
    const int t  = threadIdx.x;
    const int lo = t * SCAN_CHUNK;
    const int hi = min(lo + SCAN_CHUNK, N_NODES);

    int s = 0;
    for (int i = lo; i < hi; ++i) s += deg[i];
    part[t] = s;
    __syncthreads();
    for (int off = 1; off < SCAN_T; off <<= 1) {
        int v = (t >= off) ? part[t - off] : 0;
        __syncthreads();
        part[t] += v;
        __syncthreads();
    }
    int run = part[t] - s;   // exclusive base for this chunk
    for (int i = lo; i < hi; ++i) {
        row_start[i] = run;
        cursor[i]    = run;
        run += deg[i];
    }
    if (t == SCAN_T - 1) row_start[N_NODES] = run;  // == N_EDGES
}

// ---------------- CSR build: fill dst lists
__global__ __launch_bounds__(256) void gat_fill(const int* __restrict__ src,
                                                const int* __restrict__ dst,
                                                int* __restrict__ cursor,
                                                int* __restrict__ csr_dst) {
    const int e = blockIdx.x * 256 + threadIdx.x;
    if (e >= N_EDGES) return;
    const int pos = atomicAdd(&cursor[src[e]], 1);
    csr_dst[pos] = dst[e];
}

// ---------------- Gather: one wave per (node, head). No atomics. Fused normalize.
__global__ __launch_bounds__(256) void gat_gather(const int* __restrict__ row_start,
                                                  const int* __restrict__ csr_dst,
                                                  const float* __restrict__ h,
                                                  const float* __restrict__ ssrc,
                                                  const float* __restrict__ sdst,
                                                  float* __restrict__ out) {
    const int wid  = (int)((blockIdx.x * 256 + threadIdx.x) >> 6);
    const int lane = threadIdx.x & 63;
    if (wid >= N_NODES * NH) return;
    const int n    = wid >> 3;
    const int head = wid & 7;

    const int start = row_start[n];
    const int degn  = row_start[n + 1] - start;
    const float su  = ssrc[n * 8 + head];

    float acc = 0.f;
    float rs  = 0.f;

    for (int base = 0; base < degn; base += 64) {
        const int j = base + lane;
        int   d = 0;
        float e = 0.f;
        if (j < degn) {
            d = csr_dst[start + j];
            const float sv = su + sdst[d * 8 + head];
            const float lr = sv > 0.f ? sv : ALPHA * sv;
            e = __expf(-lr);
        }
        const int cnt = min(64, degn - base);
        for (int k = 0; k < cnt; ++k) {
            const int   dk = __shfl(d, k, 64);
            const float ek = __shfl(e, k, 64);
            acc += ek * h[(size_t)dk * HSTRIDE + head * FOUT + lane];
            rs  += ek;
        }
    }

    out[(size_t)n * HSTRIDE + head * FOUT + lane] = acc / rs;
}

extern "C" void kernel_launch(void* const* d_in, const int* in_sizes, int n_in,
                              void* d_out, int out_size, void* d_ws, size_t ws_size,
                              hipStream_t stream) {
    const float* x    = (const float*)d_in[0];
    const int*   edge = (const int*)d_in[1];
    const float* W    = (const float*)d_in[2];
    const float* a    = (const float*)d_in[3];
    float*       out  = (float*)d_out;

    char* ws = (char*)d_ws;
    size_t off = 0;
    float* h      = (float*)(ws + off); off += (size_t)N_NODES * HSTRIDE * sizeof(float); // 102.4 MB
    float* ssrc   = (float*)(ws + off); off += (size_t)N_NODES * NH * sizeof(float);
    float* sdst   = (float*)(ws + off); off += (size_t)N_NODES * NH * sizeof(float);
    int*   row_st = (int*)  (ws + off); off += (size_t)(N_NODES + 1) * sizeof(int);
    int*   cursor = (int*)  (ws + off); off += (size_t)N_NODES * sizeof(int);
    int*   deg    = (int*)  (ws + off); off += (size_t)N_NODES * sizeof(int);
    int*   csrd   = (int*)  (ws + off); off += (size_t)N_EDGES * sizeof(int);

    const int* srcv = edge;
    const int* dstv = edge + N_EDGES;

    hipMemsetAsync(deg, 0, (size_t)N_NODES * sizeof(int), stream);

    gat_proj <<<(N_NODES + 63) / 64, 256, 0, stream>>>(x, W, h);
    gat_score<<<(N_NODES * NH + 3) / 4, 256, 0, stream>>>(h, a, ssrc, sdst);
    gat_hist <<<(N_EDGES + 255) / 256, 256, 0, stream>>>(srcv, deg);
    gat_scan <<<1, SCAN_T, 0, stream>>>(deg, row_st, cursor);
    gat_fill <<<(N_EDGES + 255) / 256, 256, 0, stream>>>(srcv, dstv, cursor, csrd);
    gat_gather<<<(N_NODES * NH + 3) / 4, 256, 0, stream>>>(row_st, csrd, h, ssrc, sdst, out);
}

// Round 3
// 455.964 us; speedup vs baseline: 3.9510x; 1.6123x over previous
//
#include <hip/hip_runtime.h>
#include <hip/hip_bf16.h>
#include <math.h>

#define N_NODES 50000
#define N_EDGES 800000
#define FIN 128
#define FOUT 64
#define NH 8
#define ALPHA 0.2f
#define HSTRIDE (NH * FOUT)  // 512
#define SCAN_T 1024
#define SCAN_CHUNK ((N_NODES + SCAN_T - 1) / SCAN_T)  // 49

__device__ __forceinline__ unsigned pack_bf2(float lo, float hi) {
    __hip_bfloat162 b = __float22bfloat162_rn(make_float2(lo, hi));
    return *(unsigned*)&b;
}

// ---------------- Kernel 1: projection + fused scores.
// h2[n][col][head] bf16 (head-minor!), ssrc/sdst[n][head] f32 from f32 accumulators.
__global__ __launch_bounds__(256) void gat_proj(const float* __restrict__ x,
                                                const float* __restrict__ W,
                                                const float* __restrict__ a,
                                                __hip_bfloat16* __restrict__ h2,
                                                float* __restrict__ ssrc,
                                                float* __restrict__ sdst) {
    __shared__ float wlds[16][2][64][4];  // [ff][head-half][col][head%4]  32 KB
    __shared__ float xsm[16][32];         // [ff][node]                     2 KB

    const int t    = threadIdx.x;
    const int lane = t & 63;
    const int w    = t >> 6;
    const int n0   = blockIdx.x * 32;

    float acc[8][8];
#pragma unroll
    for (int nn = 0; nn < 8; ++nn)
#pragma unroll
        for (int i = 0; i < 8; ++i) acc[nn][i] = 0.f;

    for (int c = 0; c < 8; ++c) {
        __syncthreads();
        {
            const int ffb = w * 4;
#pragma unroll
            for (int ffo = 0; ffo < 4; ++ffo) {
                const int f = c * 16 + ffb + ffo;
#pragma unroll
                for (int hh = 0; hh < 2; ++hh) {
                    float4 v;
                    v.x = W[(size_t)(hh * 4 + 0) * (FIN * FOUT) + f * FOUT + lane];
                    v.y = W[(size_t)(hh * 4 + 1) * (FIN * FOUT) + f * FOUT + lane];
                    v.z = W[(size_t)(hh * 4 + 2) * (FIN * FOUT) + f * FOUT + lane];
                    v.w = W[(size_t)(hh * 4 + 3) * (FIN * FOUT) + f * FOUT + lane];
                    *(float4*)&wlds[ffb + ffo][hh][lane][0] = v;
                }
            }
        }
        if (t < 128) {
            const int nl = t >> 2;
            const int j4 = (t & 3) * 4;
            const int n  = n0 + nl;
            float4 v = make_float4(0.f, 0.f, 0.f, 0.f);
            if (n < N_NODES) v = *(const float4*)(x + (size_t)n * FIN + c * 16 + j4);
            xsm[j4 + 0][nl] = v.x;
            xsm[j4 + 1][nl] = v.y;
            xsm[j4 + 2][nl] = v.z;
            xsm[j4 + 3][nl] = v.w;
        }
        __syncthreads();

        for (int ff = 0; ff < 16; ++ff) {
            const float4 xa = *(const float4*)&xsm[ff][w * 8 + 0];
            const float4 xb = *(const float4*)&xsm[ff][w * 8 + 4];
            const float4 wa = *(const float4*)&wlds[ff][0][lane][0];
            const float4 wb = *(const float4*)&wlds[ff][1][lane][0];
            const float xv[8] = {xa.x, xa.y, xa.z, xa.w, xb.x, xb.y, xb.z, xb.w};
            const float wv[8] = {wa.x, wa.y, wa.z, wa.w, wb.x, wb.y, wb.z, wb.w};
#pragma unroll
            for (int nn = 0; nn < 8; ++nn)
#pragma unroll
                for (int i = 0; i < 8; ++i)
                    acc[nn][i] += xv[nn] * wv[i];
        }
    }

    float asrc[8], adst[8];
#pragma unroll
    for (int i = 0; i < 8; ++i) {
        asrc[i] = a[i * (2 * FOUT) + lane];
        adst[i] = a[i * (2 * FOUT) + FOUT + lane];
    }

#pragma unroll
    for (int nn = 0; nn < 8; ++nn) {
        const int n = n0 + w * 8 + nn;
        if (n >= N_NODES) continue;
        uint4 hv;
        hv.x = pack_bf2(acc[nn][0], acc[nn][1]);
        hv.y = pack_bf2(acc[nn][2], acc[nn][3]);
        hv.z = pack_bf2(acc[nn][4], acc[nn][5]);
        hv.w = pack_bf2(acc[nn][6], acc[nn][7]);
        *(uint4*)((char*)h2 + (size_t)n * (HSTRIDE * 2) + lane * 16) = hv;

#pragma unroll
        for (int i = 0; i < 8; ++i) {
            float p1 = acc[nn][i] * asrc[i];
            float p2 = acc[nn][i] * adst[i];
#pragma unroll
            for (int m = 1; m < 64; m <<= 1) {
                p1 += __shfl_xor(p1, m, 64);
                p2 += __shfl_xor(p2, m, 64);
            }
            if (lane == i) {
                ssrc[n * 8 + i] = p1;
                sdst[n * 8 + i] = p2;
            }
        }
    }
}

// ---------------- CSR build
__global__ __launch_bounds__(256) void gat_hist(const int* __restrict__ src,
                                                int* __restrict__ deg) {
    const int e = blockIdx.x * 256 + threadIdx.x;
    if (e < N_EDGES) atomicAdd(&deg[src[e]], 1);
}

__global__ __launch_bounds__(SCAN_T) void gat_scan(const int* __restrict__ deg,
                                                   int* __restrict__ row_start,
                                                   int* __restrict__ cursor) {
    __shared__ int part[SCAN_T];
    const int t  = threadIdx.x;
    const int lo = t * SCAN_CHUNK;
    const int hi = min(lo + SCAN_CHUNK, N_NODES);

    int s = 0;
    for (int i = lo; i < hi; ++i) s += deg[i];
    part[t] = s;
    __syncthreads();
    for (int off = 1; off < SCAN_T; off <<= 1) {
        int v = (t >= off) ? part[t - off] : 0;
        __syncthreads();
        part[t] += v;
        __syncthreads();
    }
    int run = part[t] - s;
    for (int i = lo; i < hi; ++i) {
        row_start[i] = run;
        cursor[i]    = run;
        run += deg[i];
    }
    if (t == SCAN_T - 1) row_start[N_NODES] = run;
}

__global__ __launch_bounds__(256) void gat_fill(const int* __restrict__ src,
                                                const int* __restrict__ dst,
                                                int* __restrict__ cursor,
                                                int* __restrict__ csr_dst) {
    const int e = blockIdx.x * 256 + threadIdx.x;
    if (e >= N_EDGES) return;
    const int pos = atomicAdd(&cursor[src[e]], 1);
    csr_dst[pos] = dst[e];
}

// ---------------- Gather: one wave per node, all 8 heads. One dwordx4 per lane per edge.
__global__ __launch_bounds__(256) void gat_gather(const int* __restrict__ row_start,
                                                  const int* __restrict__ csr_dst,
                                                  const __hip_bfloat16* __restrict__ h2,
                                                  const float* __restrict__ ssrc,
                                                  const float* __restrict__ sdst,
                                                  float* __restrict__ out) {
    const int n    = (int)((blockIdx.x * 256 + threadIdx.x) >> 6);
    const int lane = threadIdx.x & 63;
    if (n >= N_NODES) return;

    const int start = row_start[n];
    const int degn  = row_start[n + 1] - start;

    const float4 sa = *(const float4*)(ssrc + n * 8);
    const float4 sb = *(const float4*)(ssrc + n * 8 + 4);
    const float s0[8] = {sa.x, sa.y, sa.z, sa.w, sb.x, sb.y, sb.z, sb.w};

    float acc[8] = {0.f, 0.f, 0.f, 0.f, 0.f, 0.f, 0.f, 0.f};
    float rs[8]  = {0.f, 0.f, 0.f, 0.f, 0.f, 0.f, 0.f, 0.f};
    const unsigned lofs = (unsigned)lane * 16u;

    for (int base = 0; base < degn; base += 64) {
        const int j      = base + lane;
        const bool valid = j < degn;
        const int d = valid ? csr_dst[start + j] : 0;
        float4 qa = make_float4(0.f, 0.f, 0.f, 0.f), qb = qa;
        if (valid) {
            qa = *(const float4*)(sdst + d * 8);
            qb = *(const float4*)(sdst + d * 8 + 4);
        }
        const float q[8] = {qa.x, qa.y, qa.z, qa.w, qb.x, qb.y, qb.z, qb.w};
        float e[8];
#pragma unroll
        for (int i = 0; i < 8; ++i) {
            const float sv = s0[i] + q[i];
            const float lr = sv > 0.f ? sv : ALPHA * sv;
            e[i] = valid ? __expf(-lr) : 0.f;
            rs[i] += e[i];
        }

        const int cnt = min(64, degn - base);
        for (int k = 0; k < cnt; ++k) {
            const int dk = __builtin_amdgcn_readlane(d, k);
            float ek[8];
#pragma unroll
            for (int i = 0; i < 8; ++i)
                ek[i] = __int_as_float(__builtin_amdgcn_readlane(__float_as_int(e[i]), k));
            const uint4 hv = *(const uint4*)((const char*)h2 + ((size_t)(unsigned)dk << 10) + lofs);
            acc[0] += ek[0] * __int_as_float(hv.x << 16);
            acc[1] += ek[1] * __int_as_float(hv.x & 0xFFFF0000u);
            acc[2] += ek[2] * __int_as_float(hv.y << 16);
            acc[3] += ek[3] * __int_as_float(hv.y & 0xFFFF0000u);
            acc[4] += ek[4] * __int_as_float(hv.z << 16);
            acc[5] += ek[5] * __int_as_float(hv.z & 0xFFFF0000u);
            acc[6] += ek[6] * __int_as_float(hv.w << 16);
            acc[7] += ek[7] * __int_as_float(hv.w & 0xFFFF0000u);
        }
    }

#pragma unroll
    for (int i = 0; i < 8; ++i)
#pragma unroll
        for (int m = 1; m < 64; m <<= 1) rs[i] += __shfl_xor(rs[i], m, 64);

#pragma unroll
    for (int i = 0; i < 8; ++i)
        out[(size_t)n * HSTRIDE + i * 64 + lane] = acc[i] / rs[i];
}

extern "C" void kernel_launch(void* const* d_in, const int* in_sizes, int n_in,
                              void* d_out, int out_size, void* d_ws, size_t ws_size,
                              hipStream_t stream) {
    const float* x    = (const float*)d_in[0];
    const int*   edge = (const int*)d_in[1];
    const float* W    = (const float*)d_in[2];
    const float* a    = (const float*)d_in[3];
    float*       out  = (float*)d_out;

    char* ws = (char*)d_ws;
    size_t off = 0;
    __hip_bfloat16* h2 = (__hip_bfloat16*)(ws + off); off += (size_t)N_NODES * HSTRIDE * 2;  // 51.2 MB
    float* ssrc   = (float*)(ws + off); off += (size_t)N_NODES * NH * sizeof(float);
    float* sdst   = (float*)(ws + off); off += (size_t)N_NODES * NH * sizeof(float);
    int*   row_st = (int*)  (ws + off); off += (size_t)(N_NODES + 1) * sizeof(int);
    int*   cursor = (int*)  (ws + off); off += (size_t)N_NODES * sizeof(int);
    int*   deg    = (int*)  (ws + off); off += (size_t)N_NODES * sizeof(int);
    int*   csrd   = (int*)  (ws + off); off += (size_t)N_EDGES * sizeof(int);

    const int* srcv = edge;
    const int* dstv = edge + N_EDGES;

    hipMemsetAsync(deg, 0, (size_t)N_NODES * sizeof(int), stream);

    gat_hist <<<(N_EDGES + 255) / 256, 256, 0, stream>>>(srcv, deg);
    gat_proj <<<(N_NODES + 31) / 32, 256, 0, stream>>>(x, W, a, h2, ssrc, sdst);
    gat_scan <<<1, SCAN_T, 0, stream>>>(deg, row_st, cursor);
    gat_fill <<<(N_EDGES + 255) / 256, 256, 0, stream>>>(srcv, dstv, cursor, csrd);
    gat_gather<<<(N_NODES + 3) / 4, 256, 0, stream>>>(row_st, csrd, h2, ssrc, sdst, out);
}

// Round 4
// 419.967 us; speedup vs baseline: 4.2897x; 1.0857x over previous
//
#include <hip/hip_runtime.h>
#include <hip/hip_bf16.h>
#include <math.h>

#define N_NODES 50000
#define N_EDGES 800000
#define FIN 128
#define FOUT 64
#define NH 8
#define ALPHA 0.2f
#define HSTRIDE (NH * FOUT)  // 512
#define SCAN_T 1024
#define SCAN_CHUNK ((N_NODES + SCAN_T - 1) / SCAN_T)  // 49

typedef __attribute__((ext_vector_type(8))) short bf16x8;
typedef __attribute__((ext_vector_type(4))) float f32x4;

__device__ __forceinline__ unsigned pack_bf2(float lo, float hi) {
    __hip_bfloat162 b = __float22bfloat162_rn(make_float2(lo, hi));
    return *(unsigned*)&b;
}

// ---------------- prep: x (f32) -> xbf (bf16)
__global__ __launch_bounds__(256) void x_to_bf16(const float* __restrict__ x,
                                                 unsigned* __restrict__ xbf) {
    const size_t t = (size_t)blockIdx.x * 256 + threadIdx.x;
    const size_t i = t * 8;
    if (i >= (size_t)N_NODES * FIN) return;
    const float4 v0 = *(const float4*)(x + i);
    const float4 v1 = *(const float4*)(x + i + 4);
    uint4 o;
    o.x = pack_bf2(v0.x, v0.y);
    o.y = pack_bf2(v0.z, v0.w);
    o.z = pack_bf2(v1.x, v1.y);
    o.w = pack_bf2(v1.z, v1.w);
    *(uint4*)(xbf + t * 4) = o;
}

// ---------------- prep: BpT[dcol][k] bf16, dcol = col*8 + head (head-minor, matches h2)
__global__ __launch_bounds__(256) void build_bpt(const float* __restrict__ W,
                                                 unsigned* __restrict__ bpt) {
    const int gt = blockIdx.x * 256 + threadIdx.x;  // 16384 total
    const int dcol = gt >> 5;
    const int kq   = gt & 31;
    const int head = dcol & 7, col = dcol >> 3;
    const float* wp = W + (size_t)head * (FIN * FOUT) + (size_t)(kq * 4) * FOUT + col;
    uint2 pk;
    pk.x = pack_bf2(wp[0],        wp[FOUT]);
    pk.y = pack_bf2(wp[2 * FOUT], wp[3 * FOUT]);
    *(uint2*)(bpt + (size_t)dcol * (FIN / 2) + kq * 2) = pk;
}

// ---------------- MFMA projection: h2[n][col][head] bf16.
// Computes C^T: A = BpT (dcol x K), B = x^T (K x node). One wave = 32 nodes x all 512 dcol.
// No LDS, no barriers; x fragments live in registers across the whole dcol loop.
__global__ __launch_bounds__(256) void gat_proj(const unsigned short* __restrict__ xbf,
                                                const unsigned short* __restrict__ bpt,
                                                unsigned short* __restrict__ h2) {
    const int lane = threadIdx.x & 63;
    const int wid  = blockIdx.x * 4 + (threadIdx.x >> 6);
    const int m0   = wid * 32;
    const int l15  = lane & 15;
    const int g    = lane >> 4;   // k-subgroup 0..3

    // B-operand fragments: x^T[k][node], lane: node = m0 + nh*16 + l15, k = ks*32 + g*8 + j
    bf16x8 xf[2][4];
#pragma unroll
    for (int nh = 0; nh < 2; ++nh) {
        int node = m0 + nh * 16 + l15;
        if (node > N_NODES - 1) node = N_NODES - 1;   // clamp; stores predicated
        const unsigned short* p = xbf + (size_t)node * FIN + g * 8;
#pragma unroll
        for (int ks = 0; ks < 4; ++ks)
            xf[nh][ks] = *(const bf16x8*)(p + ks * 32);
    }

    for (int stp = 0; stp < 16; ++stp) {
        const int dc0 = stp * 32;
        f32x4 acc[2][2];
#pragma unroll
        for (int dh = 0; dh < 2; ++dh)
#pragma unroll
            for (int nh = 0; nh < 2; ++nh)
                acc[dh][nh] = (f32x4){0.f, 0.f, 0.f, 0.f};

#pragma unroll
        for (int dh = 0; dh < 2; ++dh) {
            const unsigned short* p = bpt + (size_t)(dc0 + dh * 16 + l15) * FIN + g * 8;
#pragma unroll
            for (int ks = 0; ks < 4; ++ks) {
                const bf16x8 af = *(const bf16x8*)(p + ks * 32);
                acc[dh][0] = __builtin_amdgcn_mfma_f32_16x16x32_bf16(af, xf[0][ks], acc[dh][0], 0, 0, 0);
                acc[dh][1] = __builtin_amdgcn_mfma_f32_16x16x32_bf16(af, xf[1][ks], acc[dh][1], 0, 0, 0);
            }
        }

        // D layout: row(dcol) = g*4 + reg, col(node) = l15 -> pack 4 dcol as bf16x4 (8B store)
#pragma unroll
        for (int nh = 0; nh < 2; ++nh) {
            const int node = m0 + nh * 16 + l15;
            if (node < N_NODES) {
#pragma unroll
                for (int dh = 0; dh < 2; ++dh) {
                    const int dc = dc0 + dh * 16 + g * 4;
                    uint2 pk;
                    pk.x = pack_bf2(acc[dh][nh][0], acc[dh][nh][1]);
                    pk.y = pack_bf2(acc[dh][nh][2], acc[dh][nh][3]);
                    *(uint2*)((char*)h2 + ((size_t)node * HSTRIDE + dc) * 2) = pk;
                }
            }
        }
    }
}

// ---------------- scores from h2 (bf16): wave per node, lane = col
__global__ __launch_bounds__(256) void gat_score(const unsigned short* __restrict__ h2,
                                                 const float* __restrict__ a,
                                                 float* __restrict__ ssrc,
                                                 float* __restrict__ sdst) {
    const int n    = (int)((blockIdx.x * 256 + threadIdx.x) >> 6);
    const int lane = threadIdx.x & 63;
    if (n >= N_NODES) return;

    const uint4 hv = *(const uint4*)((const char*)h2 + (size_t)n * (HSTRIDE * 2) + lane * 16);
    float h[8];
    h[0] = __int_as_float(hv.x << 16); h[1] = __int_as_float(hv.x & 0xFFFF0000u);
    h[2] = __int_as_float(hv.y << 16); h[3] = __int_as_float(hv.y & 0xFFFF0000u);
    h[4] = __int_as_float(hv.z << 16); h[5] = __int_as_float(hv.z & 0xFFFF0000u);
    h[6] = __int_as_float(hv.w << 16); h[7] = __int_as_float(hv.w & 0xFFFF0000u);

    float p1[8], p2[8];
#pragma unroll
    for (int i = 0; i < 8; ++i) {
        p1[i] = h[i] * a[i * (2 * FOUT) + lane];
        p2[i] = h[i] * a[i * (2 * FOUT) + FOUT + lane];
    }
#pragma unroll
    for (int m = 1; m < 64; m <<= 1) {
#pragma unroll
        for (int i = 0; i < 8; ++i) {
            p1[i] += __shfl_xor(p1[i], m, 64);
            p2[i] += __shfl_xor(p2[i], m, 64);
        }
    }
#pragma unroll
    for (int i = 0; i < 8; ++i) {           // static indices only (no scratch)
        if (lane == i)     ssrc[n * 8 + i] = p1[i];
        if (lane == i + 8) sdst[n * 8 + i] = p2[i];
    }
}

// ---------------- CSR build
__global__ __launch_bounds__(256) void gat_hist(const int* __restrict__ src,
                                                int* __restrict__ deg) {
    const int e = blockIdx.x * 256 + threadIdx.x;
    if (e < N_EDGES) atomicAdd(&deg[src[e]], 1);
}

__global__ __launch_bounds__(SCAN_T) void gat_scan(const int* __restrict__ deg,
                                                   int* __restrict__ row_start,
                                                   int* __restrict__ cursor) {
    __shared__ int part[SCAN_T];
    const int t  = threadIdx.x;
    const int lo = t * SCAN_CHUNK;
    const int hi = min(lo + SCAN_CHUNK, N_NODES);

    int s = 0;
    for (int i = lo; i < hi; ++i) s += deg[i];
    part[t] = s;
    __syncthreads();
    for (int off = 1; off < SCAN_T; off <<= 1) {
        int v = (t >= off) ? part[t - off] : 0;
        __syncthreads();
        part[t] += v;
        __syncthreads();
    }
    int run = part[t] - s;
    for (int i = lo; i < hi; ++i) {
        row_start[i] = run;
        cursor[i]    = run;
        run += deg[i];
    }
    if (t == SCAN_T - 1) row_start[N_NODES] = run;
}

__global__ __launch_bounds__(256) void gat_fill(const int* __restrict__ src,
                                                const int* __restrict__ dst,
                                                int* __restrict__ cursor,
                                                int* __restrict__ csr_dst) {
    const int e = blockIdx.x * 256 + threadIdx.x;
    if (e >= N_EDGES) return;
    const int pos = atomicAdd(&cursor[src[e]], 1);
    csr_dst[pos] = dst[e];
}

// ---------------- Gather: one wave per node, all 8 heads. One dwordx4 per lane per edge.
__global__ __launch_bounds__(256) void gat_gather(const int* __restrict__ row_start,
                                                  const int* __restrict__ csr_dst,
                                                  const __hip_bfloat16* __restrict__ h2,
                                                  const float* __restrict__ ssrc,
                                                  const float* __restrict__ sdst,
                                                  float* __restrict__ out) {
    const int n    = (int)((blockIdx.x * 256 + threadIdx.x) >> 6);
    const int lane = threadIdx.x & 63;
    if (n >= N_NODES) return;

    const int start = row_start[n];
    const int degn  = row_start[n + 1] - start;

    const float4 sa = *(const float4*)(ssrc + n * 8);
    const float4 sb = *(const float4*)(ssrc + n * 8 + 4);
    const float s0[8] = {sa.x, sa.y, sa.z, sa.w, sb.x, sb.y, sb.z, sb.w};

    float acc[8] = {0.f, 0.f, 0.f, 0.f, 0.f, 0.f, 0.f, 0.f};
    float rs[8]  = {0.f, 0.f, 0.f, 0.f, 0.f, 0.f, 0.f, 0.f};
    const unsigned lofs = (unsigned)lane * 16u;

    for (int base = 0; base < degn; base += 64) {
        const int j      = base + lane;
        const bool valid = j < degn;
        const int d = valid ? csr_dst[start + j] : 0;
        float4 qa = make_float4(0.f, 0.f, 0.f, 0.f), qb = qa;
        if (valid) {
            qa = *(const float4*)(sdst + d * 8);
            qb = *(const float4*)(sdst + d * 8 + 4);
        }
        const float q[8] = {qa.x, qa.y, qa.z, qa.w, qb.x, qb.y, qb.z, qb.w};
        float e[8];
#pragma unroll
        for (int i = 0; i < 8; ++i) {
            const float sv = s0[i] + q[i];
            const float lr = sv > 0.f ? sv : ALPHA * sv;
            e[i] = valid ? __expf(-lr) : 0.f;
            rs[i] += e[i];
        }

        const int cnt = min(64, degn - base);
        for (int k = 0; k < cnt; ++k) {
            const int dk = __builtin_amdgcn_readlane(d, k);
            float ek[8];
#pragma unroll
            for (int i = 0; i < 8; ++i)
                ek[i] = __int_as_float(__builtin_amdgcn_readlane(__float_as_int(e[i]), k));
            const uint4 hv = *(const uint4*)((const char*)h2 + ((size_t)(unsigned)dk << 10) + lofs);
            acc[0] += ek[0] * __int_as_float(hv.x << 16);
            acc[1] += ek[1] * __int_as_float(hv.x & 0xFFFF0000u);
            acc[2] += ek[2] * __int_as_float(hv.y << 16);
            acc[3] += ek[3] * __int_as_float(hv.y & 0xFFFF0000u);
            acc[4] += ek[4] * __int_as_float(hv.z << 16);
            acc[5] += ek[5] * __int_as_float(hv.z & 0xFFFF0000u);
            acc[6] += ek[6] * __int_as_float(hv.w << 16);
            acc[7] += ek[7] * __int_as_float(hv.w & 0xFFFF0000u);
        }
    }

#pragma unroll
    for (int i = 0; i < 8; ++i)
#pragma unroll
        for (int m = 1; m < 64; m <<= 1) rs[i] += __shfl_xor(rs[i], m, 64);

#pragma unroll
    for (int i = 0; i < 8; ++i)
        out[(size_t)n * HSTRIDE + i * 64 + lane] = acc[i] / rs[i];
}

extern "C" void kernel_launch(void* const* d_in, const int* in_sizes, int n_in,
                              void* d_out, int out_size, void* d_ws, size_t ws_size,
                              hipStream_t stream) {
    const float* x    = (const float*)d_in[0];
    const int*   edge = (const int*)d_in[1];
    const float* W    = (const float*)d_in[2];
    const float* a    = (const float*)d_in[3];
    float*       out  = (float*)d_out;

    char* ws = (char*)d_ws;
    size_t off = 0;
    unsigned short* h2  = (unsigned short*)(ws + off); off += (size_t)N_NODES * HSTRIDE * 2;  // 51.2 MB
    unsigned short* xbf = (unsigned short*)(ws + off); off += (size_t)N_NODES * FIN * 2;      // 12.8 MB
    unsigned short* bpt = (unsigned short*)(ws + off); off += (size_t)HSTRIDE * FIN * 2;      // 128 KB
    float* ssrc   = (float*)(ws + off); off += (size_t)N_NODES * NH * sizeof(float);
    float* sdst   = (float*)(ws + off); off += (size_t)N_NODES * NH * sizeof(float);
    int*   row_st = (int*)  (ws + off); off += (size_t)(N_NODES + 4) * sizeof(int);
    int*   cursor = (int*)  (ws + off); off += (size_t)N_NODES * sizeof(int);
    int*   deg    = (int*)  (ws + off); off += (size_t)N_NODES * sizeof(int);
    int*   csrd   = (int*)  (ws + off); off += (size_t)N_EDGES * sizeof(int);

    const int* srcv = edge;
    const int* dstv = edge + N_EDGES;

    hipMemsetAsync(deg, 0, (size_t)N_NODES * sizeof(int), stream);

    gat_hist  <<<(N_EDGES + 255) / 256, 256, 0, stream>>>(srcv, deg);
    x_to_bf16 <<<(N_NODES * FIN / 8 + 255) / 256, 256, 0, stream>>>(x, (unsigned*)xbf);
    build_bpt <<<(HSTRIDE * FIN / 4 + 255) / 256, 256, 0, stream>>>(W, (unsigned*)bpt);
    gat_proj  <<<(N_NODES + 127) / 128, 256, 0, stream>>>(xbf, bpt, h2);
    gat_scan  <<<1, SCAN_T, 0, stream>>>(deg, row_st, cursor);
    gat_fill  <<<(N_EDGES + 255) / 256, 256, 0, stream>>>(srcv, dstv, cursor, csrd);
    gat_score <<<(N_NODES + 3) / 4, 256, 0, stream>>>(h2, a, ssrc, sdst);
    gat_gather<<<(N_NODES + 3) / 4, 256, 0, stream>>>(row_st, csrd, (const __hip_bfloat16*)h2, ssrc, sdst, out);
}

// Round 5
// 328.247 us; speedup vs baseline: 5.4883x; 1.2794x over previous
//
#include <hip/hip_runtime.h>
#include <hip/hip_bf16.h>
#include <math.h>

#define N_NODES 50000
#define N_EDGES 800000
#define FIN 128
#define FOUT 64
#define NH 8
#define ALPHA 0.2f
#define HSTRIDE (NH * FOUT)  // 512
#define SCAN_B 196           // ceil(50000/256)

typedef __attribute__((ext_vector_type(8))) short bf16x8;
typedef __attribute__((ext_vector_type(4))) float f32x4;

__device__ __forceinline__ unsigned pack_bf2(float lo, float hi) {
    __hip_bfloat162 b = __float22bfloat162_rn(make_float2(lo, hi));
    return *(unsigned*)&b;
}

// ---------------- prep: x (f32) -> xbf (bf16)
__global__ __launch_bounds__(256) void x_to_bf16(const float* __restrict__ x,
                                                 unsigned* __restrict__ xbf) {
    const size_t t = (size_t)blockIdx.x * 256 + threadIdx.x;
    const size_t i = t * 8;
    if (i >= (size_t)N_NODES * FIN) return;
    const float4 v0 = *(const float4*)(x + i);
    const float4 v1 = *(const float4*)(x + i + 4);
    uint4 o;
    o.x = pack_bf2(v0.x, v0.y);
    o.y = pack_bf2(v0.z, v0.w);
    o.z = pack_bf2(v1.x, v1.y);
    o.w = pack_bf2(v1.z, v1.w);
    *(uint4*)(xbf + t * 4) = o;
}

// ---------------- prep: BpT[dcol][k] bf16, dcol = col*8 + head (head-minor, matches h2)
__global__ __launch_bounds__(256) void build_bpt(const float* __restrict__ W,
                                                 unsigned* __restrict__ bpt) {
    const int gt = blockIdx.x * 256 + threadIdx.x;  // 16384 total
    const int dcol = gt >> 5;
    const int kq   = gt & 31;
    const int head = dcol & 7, col = dcol >> 3;
    const float* wp = W + (size_t)head * (FIN * FOUT) + (size_t)(kq * 4) * FOUT + col;
    uint2 pk;
    pk.x = pack_bf2(wp[0],        wp[FOUT]);
    pk.y = pack_bf2(wp[2 * FOUT], wp[3 * FOUT]);
    *(uint2*)(bpt + (size_t)dcol * (FIN / 2) + kq * 2) = pk;
}

// ---------------- MFMA projection (C^T trick): h2[n][col][head] bf16
__global__ __launch_bounds__(256) void gat_proj(const unsigned short* __restrict__ xbf,
                                                const unsigned short* __restrict__ bpt,
                                                unsigned short* __restrict__ h2) {
    const int lane = threadIdx.x & 63;
    const int wid  = blockIdx.x * 4 + (threadIdx.x >> 6);
    const int m0   = wid * 32;
    const int l15  = lane & 15;
    const int g    = lane >> 4;

    bf16x8 xf[2][4];
#pragma unroll
    for (int nh = 0; nh < 2; ++nh) {
        int node = m0 + nh * 16 + l15;
        if (node > N_NODES - 1) node = N_NODES - 1;
        const unsigned short* p = xbf + (size_t)node * FIN + g * 8;
#pragma unroll
        for (int ks = 0; ks < 4; ++ks)
            xf[nh][ks] = *(const bf16x8*)(p + ks * 32);
    }

    for (int stp = 0; stp < 16; ++stp) {
        const int dc0 = stp * 32;
        f32x4 acc[2][2];
#pragma unroll
        for (int dh = 0; dh < 2; ++dh)
#pragma unroll
            for (int nh = 0; nh < 2; ++nh)
                acc[dh][nh] = (f32x4){0.f, 0.f, 0.f, 0.f};

#pragma unroll
        for (int dh = 0; dh < 2; ++dh) {
            const unsigned short* p = bpt + (size_t)(dc0 + dh * 16 + l15) * FIN + g * 8;
#pragma unroll
            for (int ks = 0; ks < 4; ++ks) {
                const bf16x8 af = *(const bf16x8*)(p + ks * 32);
                acc[dh][0] = __builtin_amdgcn_mfma_f32_16x16x32_bf16(af, xf[0][ks], acc[dh][0], 0, 0, 0);
                acc[dh][1] = __builtin_amdgcn_mfma_f32_16x16x32_bf16(af, xf[1][ks], acc[dh][1], 0, 0, 0);
            }
        }

#pragma unroll
        for (int nh = 0; nh < 2; ++nh) {
            const int node = m0 + nh * 16 + l15;
            if (node < N_NODES) {
#pragma unroll
                for (int dh = 0; dh < 2; ++dh) {
                    const int dc = dc0 + dh * 16 + g * 4;
                    uint2 pk;
                    pk.x = pack_bf2(acc[dh][nh][0], acc[dh][nh][1]);
                    pk.y = pack_bf2(acc[dh][nh][2], acc[dh][nh][3]);
                    *(uint2*)((char*)h2 + ((size_t)node * HSTRIDE + dc) * 2) = pk;
                }
            }
        }
    }
}

// ---------------- scores from h2 (bf16): wave per node, lane = col
__global__ __launch_bounds__(256) void gat_score(const unsigned short* __restrict__ h2,
                                                 const float* __restrict__ a,
                                                 float* __restrict__ ssrc,
                                                 float* __restrict__ sdst) {
    const int n    = (int)((blockIdx.x * 256 + threadIdx.x) >> 6);
    const int lane = threadIdx.x & 63;
    if (n >= N_NODES) return;

    const uint4 hv = *(const uint4*)((const char*)h2 + (size_t)n * (HSTRIDE * 2) + lane * 16);
    float h[8];
    h[0] = __int_as_float(hv.x << 16); h[1] = __int_as_float(hv.x & 0xFFFF0000u);
    h[2] = __int_as_float(hv.y << 16); h[3] = __int_as_float(hv.y & 0xFFFF0000u);
    h[4] = __int_as_float(hv.z << 16); h[5] = __int_as_float(hv.z & 0xFFFF0000u);
    h[6] = __int_as_float(hv.w << 16); h[7] = __int_as_float(hv.w & 0xFFFF0000u);

    float p1[8], p2[8];
#pragma unroll
    for (int i = 0; i < 8; ++i) {
        p1[i] = h[i] * a[i * (2 * FOUT) + lane];
        p2[i] = h[i] * a[i * (2 * FOUT) + FOUT + lane];
    }
#pragma unroll
    for (int m = 1; m < 64; m <<= 1) {
#pragma unroll
        for (int i = 0; i < 8; ++i) {
            p1[i] += __shfl_xor(p1[i], m, 64);
            p2[i] += __shfl_xor(p2[i], m, 64);
        }
    }
#pragma unroll
    for (int i = 0; i < 8; ++i) {
        if (lane == i)     ssrc[n * 8 + i] = p1[i];
        if (lane == i + 8) sdst[n * 8 + i] = p2[i];
    }
}

// ---------------- CSR build: histogram (2 edges per thread)
__global__ __launch_bounds__(256) void gat_hist(const int* __restrict__ src,
                                                int* __restrict__ deg) {
    const int e = (blockIdx.x * 256 + threadIdx.x) * 2;
    if (e + 1 < N_EDGES) {
        const int2 s2 = *(const int2*)(src + e);
        atomicAdd(&deg[s2.x], 1);
        atomicAdd(&deg[s2.y], 1);
    } else if (e < N_EDGES) {
        atomicAdd(&deg[src[e]], 1);
    }
}

// ---------------- hierarchical scan: (1) per-block sums
__global__ __launch_bounds__(256) void scan_bsum(const int* __restrict__ deg,
                                                 int* __restrict__ bsum) {
    __shared__ int sm[256];
    const int t   = threadIdx.x;
    const int gid = blockIdx.x * 256 + t;
    sm[t] = (gid < N_NODES) ? deg[gid] : 0;
    __syncthreads();
#pragma unroll
    for (int off = 128; off > 0; off >>= 1) {
        if (t < off) sm[t] += sm[t + off];
        __syncthreads();
    }
    if (t == 0) bsum[blockIdx.x] = sm[0];
}

// (2) exclusive scan of the 196 partials (single block)
__global__ __launch_bounds__(256) void scan_part(int* __restrict__ bsum) {
    __shared__ int sm[256];
    const int t = threadIdx.x;
    const int v = (t < SCAN_B) ? bsum[t] : 0;
    sm[t] = v;
    __syncthreads();
    for (int off = 1; off < 256; off <<= 1) {
        const int u = (t >= off) ? sm[t - off] : 0;
        __syncthreads();
        sm[t] += u;
        __syncthreads();
    }
    if (t < SCAN_B) bsum[t] = sm[t] - v;   // exclusive
}

// (3) per-block scan + write row_start / cursor
__global__ __launch_bounds__(256) void scan_write(const int* __restrict__ deg,
                                                  const int* __restrict__ bsum,
                                                  int* __restrict__ row_start,
                                                  int* __restrict__ cursor) {
    __shared__ int sm[256];
    const int t   = threadIdx.x;
    const int gid = blockIdx.x * 256 + t;
    const int v   = (gid < N_NODES) ? deg[gid] : 0;
    sm[t] = v;
    __syncthreads();
    for (int off = 1; off < 256; off <<= 1) {
        const int u = (t >= off) ? sm[t - off] : 0;
        __syncthreads();
        sm[t] += u;
        __syncthreads();
    }
    if (gid < N_NODES) {
        const int rs = bsum[blockIdx.x] + sm[t] - v;   // exclusive prefix
        row_start[gid] = rs;
        cursor[gid]    = rs;
    }
    if (blockIdx.x == 0 && t == 0) row_start[N_NODES] = N_EDGES;
}

__global__ __launch_bounds__(256) void gat_fill(const int* __restrict__ src,
                                                const int* __restrict__ dst,
                                                int* __restrict__ cursor,
                                                int* __restrict__ csr_dst) {
    const int e = blockIdx.x * 256 + threadIdx.x;
    if (e >= N_EDGES) return;
    const int pos = atomicAdd(&cursor[src[e]], 1);
    csr_dst[pos] = dst[e];
}

// ---------------- Gather: one wave per node, all 8 heads. NT out-stores, 2x unrolled k-loop.
__global__ __launch_bounds__(256) void gat_gather(const int* __restrict__ row_start,
                                                  const int* __restrict__ csr_dst,
                                                  const __hip_bfloat16* __restrict__ h2,
                                                  const float* __restrict__ ssrc,
                                                  const float* __restrict__ sdst,
                                                  float* __restrict__ out) {
    const int n    = (int)((blockIdx.x * 256 + threadIdx.x) >> 6);
    const int lane = threadIdx.x & 63;
    if (n >= N_NODES) return;

    const int start = row_start[n];
    const int degn  = row_start[n + 1] - start;

    const float4 sa = *(const float4*)(ssrc + n * 8);
    const float4 sb = *(const float4*)(ssrc + n * 8 + 4);
    const float s0[8] = {sa.x, sa.y, sa.z, sa.w, sb.x, sb.y, sb.z, sb.w};

    float acc[8] = {0.f, 0.f, 0.f, 0.f, 0.f, 0.f, 0.f, 0.f};
    float rs[8]  = {0.f, 0.f, 0.f, 0.f, 0.f, 0.f, 0.f, 0.f};
    const unsigned lofs = (unsigned)lane * 16u;
    const char* h2b = (const char*)h2;

    for (int base = 0; base < degn; base += 64) {
        const int j      = base + lane;
        const bool valid = j < degn;
        const int d = valid ? __builtin_nontemporal_load(csr_dst + start + j) : 0;
        float4 qa = make_float4(0.f, 0.f, 0.f, 0.f), qb = qa;
        if (valid) {
            qa = *(const float4*)(sdst + d * 8);
            qb = *(const float4*)(sdst + d * 8 + 4);
        }
        const float q[8] = {qa.x, qa.y, qa.z, qa.w, qb.x, qb.y, qb.z, qb.w};
        float e[8];
#pragma unroll
        for (int i = 0; i < 8; ++i) {
            const float sv = s0[i] + q[i];
            const float lr = sv > 0.f ? sv : ALPHA * sv;
            e[i] = valid ? __expf(-lr) : 0.f;
            rs[i] += e[i];
        }

        const int cnt = min(64, degn - base);
        int k = 0;
        for (; k + 2 <= cnt; k += 2) {
            const int dk0 = __builtin_amdgcn_readlane(d, k);
            const int dk1 = __builtin_amdgcn_readlane(d, k + 1);
            const uint4 hv0 = *(const uint4*)(h2b + ((size_t)(unsigned)dk0 << 10) + lofs);
            const uint4 hv1 = *(const uint4*)(h2b + ((size_t)(unsigned)dk1 << 10) + lofs);
            float ek0[8], ek1[8];
#pragma unroll
            for (int i = 0; i < 8; ++i) {
                ek0[i] = __int_as_float(__builtin_amdgcn_readlane(__float_as_int(e[i]), k));
                ek1[i] = __int_as_float(__builtin_amdgcn_readlane(__float_as_int(e[i]), k + 1));
            }
            acc[0] += ek0[0] * __int_as_float(hv0.x << 16);
            acc[1] += ek0[1] * __int_as_float(hv0.x & 0xFFFF0000u);
            acc[2] += ek0[2] * __int_as_float(hv0.y << 16);
            acc[3] += ek0[3] * __int_as_float(hv0.y & 0xFFFF0000u);
            acc[4] += ek0[4] * __int_as_float(hv0.z << 16);
            acc[5] += ek0[5] * __int_as_float(hv0.z & 0xFFFF0000u);
            acc[6] += ek0[6] * __int_as_float(hv0.w << 16);
            acc[7] += ek0[7] * __int_as_float(hv0.w & 0xFFFF0000u);
            acc[0] += ek1[0] * __int_as_float(hv1.x << 16);
            acc[1] += ek1[1] * __int_as_float(hv1.x & 0xFFFF0000u);
            acc[2] += ek1[2] * __int_as_float(hv1.y << 16);
            acc[3] += ek1[3] * __int_as_float(hv1.y & 0xFFFF0000u);
            acc[4] += ek1[4] * __int_as_float(hv1.z << 16);
            acc[5] += ek1[5] * __int_as_float(hv1.z & 0xFFFF0000u);
            acc[6] += ek1[6] * __int_as_float(hv1.w << 16);
            acc[7] += ek1[7] * __int_as_float(hv1.w & 0xFFFF0000u);
        }
        if (k < cnt) {
            const int dk = __builtin_amdgcn_readlane(d, k);
            const uint4 hv = *(const uint4*)(h2b + ((size_t)(unsigned)dk << 10) + lofs);
            float ek[8];
#pragma unroll
            for (int i = 0; i < 8; ++i)
                ek[i] = __int_as_float(__builtin_amdgcn_readlane(__float_as_int(e[i]), k));
            acc[0] += ek[0] * __int_as_float(hv.x << 16);
            acc[1] += ek[1] * __int_as_float(hv.x & 0xFFFF0000u);
            acc[2] += ek[2] * __int_as_float(hv.y << 16);
            acc[3] += ek[3] * __int_as_float(hv.y & 0xFFFF0000u);
            acc[4] += ek[4] * __int_as_float(hv.z << 16);
            acc[5] += ek[5] * __int_as_float(hv.z & 0xFFFF0000u);
            acc[6] += ek[6] * __int_as_float(hv.w << 16);
            acc[7] += ek[7] * __int_as_float(hv.w & 0xFFFF0000u);
        }
    }

#pragma unroll
    for (int i = 0; i < 8; ++i)
#pragma unroll
        for (int m = 1; m < 64; m <<= 1) rs[i] += __shfl_xor(rs[i], m, 64);

#pragma unroll
    for (int i = 0; i < 8; ++i)
        __builtin_nontemporal_store(acc[i] / rs[i], &out[(size_t)n * HSTRIDE + i * 64 + lane]);
}

extern "C" void kernel_launch(void* const* d_in, const int* in_sizes, int n_in,
                              void* d_out, int out_size, void* d_ws, size_t ws_size,
                              hipStream_t stream) {
    const float* x    = (const float*)d_in[0];
    const int*   edge = (const int*)d_in[1];
    const float* W    = (const float*)d_in[2];
    const float* a    = (const float*)d_in[3];
    float*       out  = (float*)d_out;

    char* ws = (char*)d_ws;
    size_t off = 0;
    unsigned short* h2  = (unsigned short*)(ws + off); off += (size_t)N_NODES * HSTRIDE * 2;
    unsigned short* xbf = (unsigned short*)(ws + off); off += (size_t)N_NODES * FIN * 2;
    unsigned short* bpt = (unsigned short*)(ws + off); off += (size_t)HSTRIDE * FIN * 2;
    float* ssrc   = (float*)(ws + off); off += (size_t)N_NODES * NH * sizeof(float);
    float* sdst   = (float*)(ws + off); off += (size_t)N_NODES * NH * sizeof(float);
    int*   row_st = (int*)  (ws + off); off += (size_t)(N_NODES + 4) * sizeof(int);
    int*   cursor = (int*)  (ws + off); off += (size_t)N_NODES * sizeof(int);
    int*   deg    = (int*)  (ws + off); off += (size_t)N_NODES * sizeof(int);
    int*   bsum   = (int*)  (ws + off); off += (size_t)256 * sizeof(int);
    int*   csrd   = (int*)  (ws + off); off += (size_t)N_EDGES * sizeof(int);

    const int* srcv = edge;
    const int* dstv = edge + N_EDGES;

    hipMemsetAsync(deg, 0, (size_t)N_NODES * sizeof(int), stream);

    gat_hist  <<<(N_EDGES / 2 + 255) / 256, 256, 0, stream>>>(srcv, deg);
    x_to_bf16 <<<(N_NODES * FIN / 8 + 255) / 256, 256, 0, stream>>>(x, (unsigned*)xbf);
    build_bpt <<<(HSTRIDE * FIN / 4 + 255) / 256, 256, 0, stream>>>(W, (unsigned*)bpt);
    gat_proj  <<<(N_NODES + 127) / 128, 256, 0, stream>>>(xbf, bpt, h2);
    scan_bsum <<<SCAN_B, 256, 0, stream>>>(deg, bsum);
    scan_part <<<1, 256, 0, stream>>>(bsum);
    scan_write<<<SCAN_B, 256, 0, stream>>>(deg, bsum, row_st, cursor);
    gat_fill  <<<(N_EDGES + 255) / 256, 256, 0, stream>>>(srcv, dstv, cursor, csrd);
    gat_score <<<(N_NODES + 3) / 4, 256, 0, stream>>>(h2, a, ssrc, sdst);
    gat_gather<<<(N_NODES + 3) / 4, 256, 0, stream>>>(row_st, csrd, (const __hip_bfloat16*)h2, ssrc, sdst, out);
}

// Round 6
// 267.289 us; speedup vs baseline: 6.7400x; 1.2281x over previous
//
#include <hip/hip_runtime.h>
#include <hip/hip_bf16.h>
#include <math.h>

#define N_NODES 50000
#define N_EDGES 800000
#define FIN 128
#define FOUT 64
#define NH 8
#define ALPHA 0.2f
#define HSTRIDE (NH * FOUT)  // 512
#define SCAN_B 196           // ceil(50000/256)

// prep kernel block ranges
#define X2BF_B 3125          // 800000 threads, 8 elems each = 6.4M
#define BPT_B  64            // 16384 threads
#define APERM_B 4            // 1024 threads
#define HIST_B 1563          // 2 edges/thread
#define PREP_B (X2BF_B + BPT_B + APERM_B + HIST_B)

typedef __attribute__((ext_vector_type(8))) short bf16x8;
typedef __attribute__((ext_vector_type(4))) float f32x4;

__device__ __forceinline__ unsigned pack_bf2(float lo, float hi) {
    __hip_bfloat162 b = __float22bfloat162_rn(make_float2(lo, hi));
    return *(unsigned*)&b;
}

// ---------------- fused prep: x->bf16 | W->BpT | a->aperm | degree histogram
__global__ __launch_bounds__(256) void gat_prep(const float* __restrict__ x,
                                                const float* __restrict__ W,
                                                const float* __restrict__ a,
                                                const int* __restrict__ src,
                                                unsigned* __restrict__ xbf,
                                                unsigned* __restrict__ bpt,
                                                float* __restrict__ aperm,
                                                int* __restrict__ deg) {
    const int b = blockIdx.x;
    const int t = threadIdx.x;

    if (b < X2BF_B) {
        const size_t tt = (size_t)b * 256 + t;
        const size_t i  = tt * 8;
        const float4 v0 = *(const float4*)(x + i);
        const float4 v1 = *(const float4*)(x + i + 4);
        uint4 o;
        o.x = pack_bf2(v0.x, v0.y);
        o.y = pack_bf2(v0.z, v0.w);
        o.z = pack_bf2(v1.x, v1.y);
        o.w = pack_bf2(v1.z, v1.w);
        *(uint4*)(xbf + tt * 4) = o;
    } else if (b < X2BF_B + BPT_B) {
        const int gt   = (b - X2BF_B) * 256 + t;  // 16384
        const int dcol = gt >> 5;
        const int kq   = gt & 31;
        const int head = dcol & 7, col = dcol >> 3;
        const float* wp = W + (size_t)head * (FIN * FOUT) + (size_t)(kq * 4) * FOUT + col;
        uint2 pk;
        pk.x = pack_bf2(wp[0],        wp[FOUT]);
        pk.y = pack_bf2(wp[2 * FOUT], wp[3 * FOUT]);
        *(uint2*)(bpt + (size_t)dcol * (FIN / 2) + kq * 2) = pk;
    } else if (b < X2BF_B + BPT_B + APERM_B) {
        const int idx  = (b - X2BF_B - BPT_B) * 256 + t;  // 0..1023
        const int tab  = idx >> 9;                        // 0 = src, 1 = dst
        const int dcol = idx & 511;
        aperm[idx] = a[(dcol & 7) * (2 * FOUT) + tab * FOUT + (dcol >> 3)];
    } else {
        const int e = ((b - X2BF_B - BPT_B - APERM_B) * 256 + t) * 2;
        if (e + 1 < N_EDGES) {
            const int2 s2 = *(const int2*)(src + e);
            atomicAdd(&deg[s2.x], 1);
            atomicAdd(&deg[s2.y], 1);
        } else if (e < N_EDGES) {
            atomicAdd(&deg[src[e]], 1);
        }
    }
}

// ---------------- MFMA projection + fused scores.
// h2[n][col][head] bf16; ssrc/sdst[n][head] f32 from the f32 MFMA accumulators.
// D layout: row(dcol-local) = g*4 + reg, col(node-local) = l15. head = (g*4+r)&7.
__global__ __launch_bounds__(256) void gat_proj(const unsigned short* __restrict__ xbf,
                                                const unsigned short* __restrict__ bpt,
                                                const float* __restrict__ aperm,
                                                unsigned short* __restrict__ h2,
                                                float* __restrict__ ssrc,
                                                float* __restrict__ sdst) {
    const int lane = threadIdx.x & 63;
    const int wid  = blockIdx.x * 4 + (threadIdx.x >> 6);
    const int m0   = wid * 32;
    const int l15  = lane & 15;
    const int g    = lane >> 4;

    bf16x8 xf[2][4];
#pragma unroll
    for (int nh = 0; nh < 2; ++nh) {
        int node = m0 + nh * 16 + l15;
        if (node > N_NODES - 1) node = N_NODES - 1;
        const unsigned short* p = xbf + (size_t)node * FIN + g * 8;
#pragma unroll
        for (int ks = 0; ks < 4; ++ks)
            xf[nh][ks] = *(const bf16x8*)(p + ks * 32);
    }

    float sc1[2][4], sc2[2][4];
#pragma unroll
    for (int nh = 0; nh < 2; ++nh)
#pragma unroll
        for (int r = 0; r < 4; ++r) { sc1[nh][r] = 0.f; sc2[nh][r] = 0.f; }

    for (int stp = 0; stp < 16; ++stp) {
        const int dc0 = stp * 32;
        f32x4 acc[2][2];
#pragma unroll
        for (int dh = 0; dh < 2; ++dh)
#pragma unroll
            for (int nh = 0; nh < 2; ++nh)
                acc[dh][nh] = (f32x4){0.f, 0.f, 0.f, 0.f};

#pragma unroll
        for (int dh = 0; dh < 2; ++dh) {
            const unsigned short* p = bpt + (size_t)(dc0 + dh * 16 + l15) * FIN + g * 8;
#pragma unroll
            for (int ks = 0; ks < 4; ++ks) {
                const bf16x8 af = *(const bf16x8*)(p + ks * 32);
                acc[dh][0] = __builtin_amdgcn_mfma_f32_16x16x32_bf16(af, xf[0][ks], acc[dh][0], 0, 0, 0);
                acc[dh][1] = __builtin_amdgcn_mfma_f32_16x16x32_bf16(af, xf[1][ks], acc[dh][1], 0, 0, 0);
            }
        }

        // fused score partials: lane (g,r) owns head (4g+r)&7, even-or-odd cols
#pragma unroll
        for (int dh = 0; dh < 2; ++dh) {
            const float4 ap1 = *(const float4*)&aperm[dc0 + dh * 16 + g * 4];
            const float4 ap2 = *(const float4*)&aperm[512 + dc0 + dh * 16 + g * 4];
#pragma unroll
            for (int nh = 0; nh < 2; ++nh) {
                sc1[nh][0] += acc[dh][nh][0] * ap1.x;  sc2[nh][0] += acc[dh][nh][0] * ap2.x;
                sc1[nh][1] += acc[dh][nh][1] * ap1.y;  sc2[nh][1] += acc[dh][nh][1] * ap2.y;
                sc1[nh][2] += acc[dh][nh][2] * ap1.z;  sc2[nh][2] += acc[dh][nh][2] * ap2.z;
                sc1[nh][3] += acc[dh][nh][3] * ap1.w;  sc2[nh][3] += acc[dh][nh][3] * ap2.w;
            }
        }

#pragma unroll
        for (int nh = 0; nh < 2; ++nh) {
            const int node = m0 + nh * 16 + l15;
            if (node < N_NODES) {
#pragma unroll
                for (int dh = 0; dh < 2; ++dh) {
                    const int dc = dc0 + dh * 16 + g * 4;
                    uint2 pk;
                    pk.x = pack_bf2(acc[dh][nh][0], acc[dh][nh][1]);
                    pk.y = pack_bf2(acc[dh][nh][2], acc[dh][nh][3]);
                    *(uint2*)((char*)h2 + ((size_t)node * HSTRIDE + dc) * 2) = pk;
                }
            }
        }
    }

    // combine col-parity partner (g ^ 2) and write scores: g=0 -> heads 0..3, g=1 -> heads 4..7
#pragma unroll
    for (int nh = 0; nh < 2; ++nh) {
        const int node = m0 + nh * 16 + l15;
        float4 v1 = make_float4(sc1[nh][0], sc1[nh][1], sc1[nh][2], sc1[nh][3]);
        float4 v2 = make_float4(sc2[nh][0], sc2[nh][1], sc2[nh][2], sc2[nh][3]);
        v1.x += __shfl_xor(v1.x, 32, 64); v1.y += __shfl_xor(v1.y, 32, 64);
        v1.z += __shfl_xor(v1.z, 32, 64); v1.w += __shfl_xor(v1.w, 32, 64);
        v2.x += __shfl_xor(v2.x, 32, 64); v2.y += __shfl_xor(v2.y, 32, 64);
        v2.z += __shfl_xor(v2.z, 32, 64); v2.w += __shfl_xor(v2.w, 32, 64);
        if (node < N_NODES) {
            if (g == 0) { *(float4*)&ssrc[node * 8]     = v1; *(float4*)&sdst[node * 8]     = v2; }
            if (g == 1) { *(float4*)&ssrc[node * 8 + 4] = v1; *(float4*)&sdst[node * 8 + 4] = v2; }
        }
    }
}

// ---------------- hierarchical scan
__global__ __launch_bounds__(256) void scan_bsum(const int* __restrict__ deg,
                                                 int* __restrict__ bsum) {
    __shared__ int sm[256];
    const int t   = threadIdx.x;
    const int gid = blockIdx.x * 256 + t;
    sm[t] = (gid < N_NODES) ? deg[gid] : 0;
    __syncthreads();
#pragma unroll
    for (int off = 128; off > 0; off >>= 1) {
        if (t < off) sm[t] += sm[t + off];
        __syncthreads();
    }
    if (t == 0) bsum[blockIdx.x] = sm[0];
}

__global__ __launch_bounds__(256) void scan_part(int* __restrict__ bsum) {
    __shared__ int sm[256];
    const int t = threadIdx.x;
    const int v = (t < SCAN_B) ? bsum[t] : 0;
    sm[t] = v;
    __syncthreads();
    for (int off = 1; off < 256; off <<= 1) {
        const int u = (t >= off) ? sm[t - off] : 0;
        __syncthreads();
        sm[t] += u;
        __syncthreads();
    }
    if (t < SCAN_B) bsum[t] = sm[t] - v;
}

__global__ __launch_bounds__(256) void scan_write(const int* __restrict__ deg,
                                                  const int* __restrict__ bsum,
                                                  int* __restrict__ row_start,
                                                  int* __restrict__ cursor) {
    __shared__ int sm[256];
    const int t   = threadIdx.x;
    const int gid = blockIdx.x * 256 + t;
    const int v   = (gid < N_NODES) ? deg[gid] : 0;
    sm[t] = v;
    __syncthreads();
    for (int off = 1; off < 256; off <<= 1) {
        const int u = (t >= off) ? sm[t - off] : 0;
        __syncthreads();
        sm[t] += u;
        __syncthreads();
    }
    if (gid < N_NODES) {
        const int rs = bsum[blockIdx.x] + sm[t] - v;
        row_start[gid] = rs;
        cursor[gid]    = rs;
    }
    if (blockIdx.x == 0 && t == 0) row_start[N_NODES] = N_EDGES;
}

__global__ __launch_bounds__(256) void gat_fill(const int* __restrict__ src,
                                                const int* __restrict__ dst,
                                                int* __restrict__ cursor,
                                                int* __restrict__ csr_dst) {
    const int e = blockIdx.x * 256 + threadIdx.x;
    if (e >= N_EDGES) return;
    const int pos = atomicAdd(&cursor[src[e]], 1);
    csr_dst[pos] = dst[e];
}

// ---------------- Gather: wave per node, 4-deep software-pipelined h2 loads.
#define GAT_LD(KK) (*(const uint4*)(h2b + ((size_t)(unsigned)__builtin_amdgcn_readlane(d, (KK)) << 10) + lofs))

#define GAT_FMA(HV, KK) do {                                                          \
    const float e0 = __int_as_float(__builtin_amdgcn_readlane(__float_as_int(e[0]), (KK))); \
    const float e1 = __int_as_float(__builtin_amdgcn_readlane(__float_as_int(e[1]), (KK))); \
    const float e2 = __int_as_float(__builtin_amdgcn_readlane(__float_as_int(e[2]), (KK))); \
    const float e3 = __int_as_float(__builtin_amdgcn_readlane(__float_as_int(e[3]), (KK))); \
    const float e4 = __int_as_float(__builtin_amdgcn_readlane(__float_as_int(e[4]), (KK))); \
    const float e5 = __int_as_float(__builtin_amdgcn_readlane(__float_as_int(e[5]), (KK))); \
    const float e6 = __int_as_float(__builtin_amdgcn_readlane(__float_as_int(e[6]), (KK))); \
    const float e7 = __int_as_float(__builtin_amdgcn_readlane(__float_as_int(e[7]), (KK))); \
    acc[0] += e0 * __int_as_float((HV).x << 16);                                      \
    acc[1] += e1 * __int_as_float((HV).x & 0xFFFF0000u);                              \
    acc[2] += e2 * __int_as_float((HV).y << 16);                                      \
    acc[3] += e3 * __int_as_float((HV).y & 0xFFFF0000u);                              \
    acc[4] += e4 * __int_as_float((HV).z << 16);                                      \
    acc[5] += e5 * __int_as_float((HV).z & 0xFFFF0000u);                              \
    acc[6] += e6 * __int_as_float((HV).w << 16);                                      \
    acc[7] += e7 * __int_as_float((HV).w & 0xFFFF0000u);                              \
} while (0)

__global__ __launch_bounds__(256) void gat_gather(const int* __restrict__ row_start,
                                                  const int* __restrict__ csr_dst,
                                                  const __hip_bfloat16* __restrict__ h2,
                                                  const float* __restrict__ ssrc,
                                                  const float* __restrict__ sdst,
                                                  float* __restrict__ out) {
    const int n    = (int)((blockIdx.x * 256 + threadIdx.x) >> 6);
    const int lane = threadIdx.x & 63;
    if (n >= N_NODES) return;

    const int start = row_start[n];
    const int degn  = row_start[n + 1] - start;

    const float4 sa = *(const float4*)(ssrc + n * 8);
    const float4 sb = *(const float4*)(ssrc + n * 8 + 4);
    const float s0[8] = {sa.x, sa.y, sa.z, sa.w, sb.x, sb.y, sb.z, sb.w};

    float acc[8] = {0.f, 0.f, 0.f, 0.f, 0.f, 0.f, 0.f, 0.f};
    float rs[8]  = {0.f, 0.f, 0.f, 0.f, 0.f, 0.f, 0.f, 0.f};
    const unsigned lofs = (unsigned)lane * 16u;
    const char* h2b = (const char*)h2;

    for (int base = 0; base < degn; base += 64) {
        const int j      = base + lane;
        const bool valid = j < degn;
        const int d = valid ? __builtin_nontemporal_load(csr_dst + start + j) : 0;
        float4 qa = make_float4(0.f, 0.f, 0.f, 0.f), qb = qa;
        if (valid) {
            qa = *(const float4*)(sdst + d * 8);
            qb = *(const float4*)(sdst + d * 8 + 4);
        }
        const float q[8] = {qa.x, qa.y, qa.z, qa.w, qb.x, qb.y, qb.z, qb.w};
        float e[8];
#pragma unroll
        for (int i = 0; i < 8; ++i) {
            const float sv = s0[i] + q[i];
            const float lr = sv > 0.f ? sv : ALPHA * sv;
            e[i] = valid ? __expf(-lr) : 0.f;
            rs[i] += e[i];
        }

        const int cnt = min(64, degn - base);
        int k = 0;
        if (cnt >= 8) {
            uint4 q0 = GAT_LD(0), q1 = GAT_LD(1), q2 = GAT_LD(2), q3 = GAT_LD(3);
            for (k = 0; k + 8 <= cnt; k += 4) {
                GAT_FMA(q0, k + 0); q0 = GAT_LD(k + 4);
                GAT_FMA(q1, k + 1); q1 = GAT_LD(k + 5);
                GAT_FMA(q2, k + 2); q2 = GAT_LD(k + 6);
                GAT_FMA(q3, k + 3); q3 = GAT_LD(k + 7);
            }
            GAT_FMA(q0, k + 0);
            GAT_FMA(q1, k + 1);
            GAT_FMA(q2, k + 2);
            GAT_FMA(q3, k + 3);
            k += 4;
        }
        for (; k < cnt; ++k) {
            const uint4 qv = GAT_LD(k);
            GAT_FMA(qv, k);
        }
    }

#pragma unroll
    for (int i = 0; i < 8; ++i)
#pragma unroll
        for (int m = 1; m < 64; m <<= 1) rs[i] += __shfl_xor(rs[i], m, 64);

#pragma unroll
    for (int i = 0; i < 8; ++i)
        __builtin_nontemporal_store(acc[i] / rs[i], &out[(size_t)n * HSTRIDE + i * 64 + lane]);
}

extern "C" void kernel_launch(void* const* d_in, const int* in_sizes, int n_in,
                              void* d_out, int out_size, void* d_ws, size_t ws_size,
                              hipStream_t stream) {
    const float* x    = (const float*)d_in[0];
    const int*   edge = (const int*)d_in[1];
    const float* W    = (const float*)d_in[2];
    const float* a    = (const float*)d_in[3];
    float*       out  = (float*)d_out;

    char* ws = (char*)d_ws;
    size_t off = 0;
    unsigned short* h2  = (unsigned short*)(ws + off); off += (size_t)N_NODES * HSTRIDE * 2;
    unsigned short* xbf = (unsigned short*)(ws + off); off += (size_t)N_NODES * FIN * 2;
    unsigned short* bpt = (unsigned short*)(ws + off); off += (size_t)HSTRIDE * FIN * 2;
    float* aperm  = (float*)(ws + off); off += (size_t)2 * HSTRIDE * sizeof(float);
    float* ssrc   = (float*)(ws + off); off += (size_t)N_NODES * NH * sizeof(float);
    float* sdst   = (float*)(ws + off); off += (size_t)N_NODES * NH * sizeof(float);
    int*   row_st = (int*)  (ws + off); off += (size_t)(N_NODES + 4) * sizeof(int);
    int*   cursor = (int*)  (ws + off); off += (size_t)N_NODES * sizeof(int);
    int*   deg    = (int*)  (ws + off); off += (size_t)N_NODES * sizeof(int);
    int*   bsum   = (int*)  (ws + off); off += (size_t)256 * sizeof(int);
    int*   csrd   = (int*)  (ws + off); off += (size_t)N_EDGES * sizeof(int);

    const int* srcv = edge;
    const int* dstv = edge + N_EDGES;

    hipMemsetAsync(deg, 0, (size_t)N_NODES * sizeof(int), stream);

    gat_prep  <<<PREP_B, 256, 0, stream>>>(x, W, a, srcv, (unsigned*)xbf, (unsigned*)bpt, aperm, deg);
    gat_proj  <<<(N_NODES + 127) / 128, 256, 0, stream>>>(xbf, bpt, aperm, h2, ssrc, sdst);
    scan_bsum <<<SCAN_B, 256, 0, stream>>>(deg, bsum);
    scan_part <<<1, 256, 0, stream>>>(bsum);
    scan_write<<<SCAN_B, 256, 0, stream>>>(deg, bsum, row_st, cursor);
    gat_fill  <<<(N_EDGES + 255) / 256, 256, 0, stream>>>(srcv, dstv, cursor, csrd);
    gat_gather<<<(N_NODES + 3) / 4, 256, 0, stream>>>(row_st, csrd, (const __hip_bfloat16*)h2, ssrc, sdst, out);
}